// Round 1
// baseline (582.833 us; speedup 1.0000x reference)
//
#include <hip/hip_runtime.h>

// LogicGatedSNN: fused single-pass kernel.
//   IN_FEATURES = OUT_FEATURES = 8192, THRESHOLD = 50.0
// One block per output row:
//   phase 1: current = sum_i x[i] * (syn[row,i] > 50)   (row streamed as float4)
//   phase 2: LIF update -> spike, v_new (thread 0, broadcast via LDS)
//   phase 3: trace_new[row,i] = clip(trace*0.7 + spike*x[i], 0, 3)
// x (32 KB) is loaded once per block into registers (8 x float4 per thread)
// and reused across both phases; it stays L2-resident across blocks.

#define IN_F 8192
#define OUT_F 8192
#define SYN_THRESH 50.0f

__global__ __launch_bounds__(256) void snn_fused_kernel(
    const float* __restrict__ x,      // [IN_F] spike_input (0/1)
    const float* __restrict__ syn,    // [OUT_F, IN_F] synapse_states
    const float* __restrict__ mp,     // [OUT_F] membrane_potential
    const float* __restrict__ thr,    // [OUT_F] adaptive_threshold
    const float* __restrict__ trace,  // [OUT_F, IN_F] eligibility_trace
    float* __restrict__ out_spikes,   // [OUT_F]
    float* __restrict__ out_vnew,     // [OUT_F]
    float* __restrict__ out_trace)    // [OUT_F, IN_F]
{
    const int row = blockIdx.x;
    const int tid = threadIdx.x;
    const long long base = (long long)row * IN_F;

    const float4* __restrict__ x4   = (const float4*)x;
    const float4* __restrict__ syn4 = (const float4*)(syn + base);
    const float4* __restrict__ tr4  = (const float4*)(trace + base);
    float4* __restrict__ ot4        = (float4*)(out_trace + base);

    // 8192 floats / 4 = 2048 float4 per row; 256 threads -> 8 float4/thread.
    float4 xv[8];
    float sum = 0.0f;
#pragma unroll
    for (int j = 0; j < 8; ++j) {
        const int idx = j * 256 + tid;          // coalesced: lane-contiguous
        xv[j] = x4[idx];
        const float4 s = syn4[idx];
        sum += ((s.x > SYN_THRESH) ? xv[j].x : 0.0f)
             + ((s.y > SYN_THRESH) ? xv[j].y : 0.0f)
             + ((s.z > SYN_THRESH) ? xv[j].z : 0.0f)
             + ((s.w > SYN_THRESH) ? xv[j].w : 0.0f);
    }

    // Wave (64-lane) shuffle reduction.
#pragma unroll
    for (int off = 32; off > 0; off >>= 1)
        sum += __shfl_down(sum, off, 64);

    __shared__ float wave_sums[4];
    __shared__ float s_spike;
    const int wave = tid >> 6;
    if ((tid & 63) == 0) wave_sums[wave] = sum;
    __syncthreads();

    if (tid == 0) {
        const float current = wave_sums[0] + wave_sums[1] + wave_sums[2] + wave_sums[3];
        const float v = mp[row] * 0.6f + current;
        const float spike = (v >= thr[row]) ? 1.0f : 0.0f;
        out_spikes[row] = spike;
        out_vnew[row]   = v * (1.0f - spike) * 0.3f;
        s_spike = spike;
    }
    __syncthreads();
    const float spike = s_spike;

#pragma unroll
    for (int j = 0; j < 8; ++j) {
        const int idx = j * 256 + tid;
        float4 t = tr4[idx];
        t.x = fminf(fmaxf(t.x * 0.7f + spike * xv[j].x, 0.0f), 3.0f);
        t.y = fminf(fmaxf(t.y * 0.7f + spike * xv[j].y, 0.0f), 3.0f);
        t.z = fminf(fmaxf(t.z * 0.7f + spike * xv[j].z, 0.0f), 3.0f);
        t.w = fminf(fmaxf(t.w * 0.7f + spike * xv[j].w, 0.0f), 3.0f);
        ot4[idx] = t;
    }
}

extern "C" void kernel_launch(void* const* d_in, const int* in_sizes, int n_in,
                              void* d_out, int out_size, void* d_ws, size_t ws_size,
                              hipStream_t stream) {
    const float* x     = (const float*)d_in[0];  // spike_input      [1, 8192]
    const float* syn   = (const float*)d_in[1];  // synapse_states   [8192, 8192]
    const float* mp    = (const float*)d_in[2];  // membrane_potential [8192]
    const float* thr   = (const float*)d_in[3];  // adaptive_threshold [8192]
    const float* trace = (const float*)d_in[4];  // eligibility_trace [8192, 8192]

    float* out = (float*)d_out;
    float* out_spikes = out;                       // [8192]
    float* out_vnew   = out + OUT_F;               // [8192]
    float* out_trace  = out + 2 * OUT_F;           // [8192, 8192]

    snn_fused_kernel<<<OUT_F, 256, 0, stream>>>(
        x, syn, mp, thr, trace, out_spikes, out_vnew, out_trace);
}